// Round 18
// baseline (102.186 us; speedup 1.0000x reference)
//
#include <hip/hip_runtime.h>

// Problem constants (from reference)
#define NS   1000        // N_SAMPLES
#define NB   32          // batch
#define NK   27          // cluster channels
#define KP   28          // padded K (for float4)
#define HW   65536       // 256*256
#define OUT_F4 8000000   // NB*NS*NS / 4
// sim = 10*exp(-cd/1.0 - gd/0.3) + 3*exp(-10*cd)
// SPARSITY (validated R13/R14): cd >= 30 => sim underflows (|masked| <= ~1e-9
// << threshold 16.88) => emit exact 0, skip all data access (99.7% of pairs).
// R18: 3-kernel split — {pure fill @ write BW} + {gather} + {sparse writer}.

// ws layout (floats):
//   selc [NB][NS][KP]  : 896000
//   selg [NB][NS][4]   : 128000   (offset 896000)
//   cf   [NS][2]       : 2000     (offset 1024000)
#define OFF_SELG 896000
#define OFF_CF   1024000

typedef __attribute__((ext_vector_type(4))) float f32x4;

// ---- K0: pure zero-fill of out, grid-stride f32x4 (target ~7 TB/s) ----
__global__ __launch_bounds__(256) void crf_fill(float* __restrict__ out) {
    const int stride = gridDim.x * 256;          // threads
    int idx = blockIdx.x * 256 + threadIdx.x;
    f32x4 z = {0.0f, 0.0f, 0.0f, 0.0f};
    #pragma unroll 4
    for (; idx < OUT_F4; idx += stride)
        *(f32x4*)(out + (long)idx * 4) = z;
}

// ---- K1: gather, one thread per (n, i, ch), ch in [0,32) (R10 verbatim) ----
__global__ void crf_gather(const float* __restrict__ guidance,
                           const float* __restrict__ clusters,
                           const int* __restrict__ coords,
                           float* __restrict__ ws) {
    int tid = blockIdx.x * 256 + threadIdx.x;
    if (tid >= NB * NS * 32) return;
    int ch = tid & 31;
    int ni = tid >> 5;
    int n = ni / NS;
    int i = ni - n * NS;
    int r = coords[i];
    int c = coords[NS + i];
    int pix = r * 256 + c;

    if (ch < KP) {
        float v = 0.0f;
        if (ch < NK)
            v = clusters[((long)n * NK + ch) * HW + pix];
        ws[(long)ni * KP + ch] = v;
    } else {
        int g = ch - KP;  // 0..3
        float v = 0.0f;
        if (g < 3)
            v = guidance[((long)n * 3 + g) * HW + pix];
        ws[OFF_SELG + (long)ni * 4 + g] = v;
        if (g == 3 && n == 0) {
            ws[OFF_CF + i * 2]     = (float)r;
            ws[OFF_CF + i * 2 + 1] = (float)c;
        }
    }
}

// ---- K2: sparse writer — one thread per (a,b) pair; ~0.3% active ----
__global__ __launch_bounds__(256) void crf_sparse(const float* __restrict__ ws,
                                                  float* __restrict__ out) {
    int pair = blockIdx.x * 256 + threadIdx.x;
    if (pair >= NS * NS) return;
    int a = pair / NS;
    int b = pair - a * NS;

    const float* __restrict__ cf = ws + OFF_CF;
    float dr = cf[2 * a]     - cf[2 * b];
    float dc = cf[2 * a + 1] - cf[2 * b + 1];
    float cd = dr * dr + dc * dc;
    if (cd >= 30.0f) return;          // out stays 0

    const float* __restrict__ selc = ws;
    const float* __restrict__ selg = ws + OFF_SELG;
    const float e2 = 3.0f * __expf(-10.0f * cd);

    for (int n = 0; n < NB; ++n) {
        const float4* pa4 = (const float4*)(selc + ((long)n * NS + a) * KP);
        const float4* pb4 = (const float4*)(selc + ((long)n * NS + b) * KP);
        float dot = 0.0f;
        #pragma unroll
        for (int j = 0; j < 7; ++j) {
            float4 va = pa4[j], vb = pb4[j];
            dot += va.x * vb.x;
            dot += va.y * vb.y;
            dot += va.z * vb.z;
            dot += va.w * vb.w;
        }
        const float* ga = selg + ((long)n * NS + a) * 4;
        const float* gb = selg + ((long)n * NS + b) * 4;
        float g0 = ga[0] - gb[0], g1 = ga[1] - gb[1], g2 = ga[2] - gb[2];
        float gd = g0 * g0 + g1 * g1 + g2 * g2;
        float s = 10.0f * __expf(-cd - gd * (1.0f / 0.3f)) + e2;
        out[((long)n * NS + a) * NS + b] = -dot * s;
    }
}

extern "C" void kernel_launch(void* const* d_in, const int* in_sizes, int n_in,
                              void* d_out, int out_size, void* d_ws, size_t ws_size,
                              hipStream_t stream) {
    const float* guidance = (const float*)d_in[0];
    const float* clusters = (const float*)d_in[1];
    const int*   coords   = (const int*)d_in[2];
    float* out = (float*)d_out;
    float* ws  = (float*)d_ws;

    // K0: zero-fill 128 MB at write BW
    crf_fill<<<2048, 256, 0, stream>>>(out);
    // K1: gather (scattered-read phase, at fetch floor)
    {
        int total = NB * NS * 32;
        int blocks = (total + 255) / 256;
        crf_gather<<<blocks, 256, 0, stream>>>(guidance, clusters, coords, ws);
    }
    // K2: sparse compute + overwrite (~2800 pairs x 32 batches)
    crf_sparse<<<(NS * NS + 255) / 256, 256, 0, stream>>>(ws, out);
}

// Round 19
// 53.719 us; speedup vs baseline: 1.9022x; 1.9022x over previous
//
#include <hip/hip_runtime.h>

// Problem constants (from reference)
#define NS   1000        // N_SAMPLES
#define NB   32          // batch
#define NK   27          // cluster channels
#define KP   28          // padded K (for float4)
#define HW   65536       // 256*256
// sim = 10*exp(-cd/1.0 - gd/0.3) + 3*exp(-10*cd)
// SPARSITY (validated R13/R14): cd >= 30 => sim underflows (|masked| <= ~1e-9
// << threshold 16.88) => emit exact 0, skip all data access (99.7% of pairs).
// R19: R17 base + RA=10 (3200 blocks, CU-imbalance 1.12x -> 1.04x) + hoisted
// per-row coord loads (break per-iteration s_load -> gate -> store chain).

// ws layout (floats):
//   selc [NB][NS][KP]  : 896000
//   selg [NB][NS][4]   : 128000   (offset 896000)
//   cf   [NS][2]       : 2000     (offset 1024000)
#define OFF_SELG 896000
#define OFF_CF   1024000

typedef __attribute__((ext_vector_type(4))) float f32x4;

// gather: one thread per (n, i, ch), ch in [0,32)  (R10 verbatim)
__global__ void crf_gather(const float* __restrict__ guidance,
                           const float* __restrict__ clusters,
                           const int* __restrict__ coords,
                           float* __restrict__ ws) {
    int tid = blockIdx.x * 256 + threadIdx.x;
    if (tid >= NB * NS * 32) return;
    int ch = tid & 31;
    int ni = tid >> 5;
    int n = ni / NS;
    int i = ni - n * NS;
    int r = coords[i];
    int c = coords[NS + i];
    int pix = r * 256 + c;

    if (ch < KP) {
        float v = 0.0f;
        if (ch < NK)
            v = clusters[((long)n * NK + ch) * HW + pix];
        ws[(long)ni * KP + ch] = v;
    } else {
        int g = ch - KP;  // 0..3
        float v = 0.0f;
        if (g < 3)
            v = guidance[((long)n * 3 + g) * HW + pix];
        ws[OFF_SELG + (long)ni * 4 + g] = v;
        if (g == 3 && n == 0) {
            ws[OFF_CF + i * 2]     = (float)r;
            ws[OFF_CF + i * 2 + 1] = (float)c;
        }
    }
}

#define RA     10          // a-rows per block
#define NCHUNK 100         // NS / RA

// main: block = (n, 10 a-rows); 256 threads; thread t<250 owns b = 4t..4t+3,
// ONE f32x4 store per row. All row coords hoisted before the loop.
__global__ __launch_bounds__(256) void crf_main(const float* __restrict__ ws,
                                                float* __restrict__ out) {
    const int bid = blockIdx.x;
    const int n = bid / NCHUNK;
    const int a0 = (bid - n * NCHUNK) * RA;
    const int t = threadIdx.x;

    const float* __restrict__ selc = ws;
    const float* __restrict__ selg = ws + OFF_SELG;
    const float* __restrict__ cf   = ws + OFF_CF;

    const bool act = (t < 250);
    const int b4 = 4 * t;                    // 0..996

    float xbr[4], xbc[4];
    if (act) {
        #pragma unroll
        for (int j = 0; j < 4; ++j) {
            xbr[j] = cf[2 * (b4 + j)];
            xbc[j] = cf[2 * (b4 + j) + 1];
        }
    }

    // hoist all RA rows' coords (wave-uniform, contiguous 20 floats)
    float xars[RA], xacs[RA];
    #pragma unroll
    for (int a = 0; a < RA; ++a) {
        xars[a] = cf[2 * (a0 + a)];
        xacs[a] = cf[2 * (a0 + a) + 1];
    }

    #pragma unroll
    for (int a = 0; a < RA; ++a) {
        const int ai = a0 + a;
        const long arow = (long)n * NS + ai;
        const float xar = xars[a], xac = xacs[a];

        // uniform a-row data (scalarized by compiler)
        const float4* pa4 = (const float4*)(selc + arow * KP);
        float4 pa[7];
        #pragma unroll
        for (int j = 0; j < 7; ++j) pa[j] = pa4[j];
        const float* pga = selg + arow * 4;
        const float ga0 = pga[0], ga1 = pga[1], ga2 = pga[2];

        if (act) {
            f32x4 res = {0.0f, 0.0f, 0.0f, 0.0f};
            #pragma unroll
            for (int j = 0; j < 4; ++j) {
                float dr = xar - xbr[j], dc = xac - xbc[j];
                float cd = dr * dr + dc * dc;
                if (cd < 30.0f) {
                    const long brow = (long)n * NS + b4 + j;
                    const float4* pb4 = (const float4*)(selc + brow * KP);
                    float dot = 0.0f;
                    #pragma unroll
                    for (int q = 0; q < 7; ++q) {
                        float4 va = pa[q], vb = pb4[q];
                        dot += va.x * vb.x;
                        dot += va.y * vb.y;
                        dot += va.z * vb.z;
                        dot += va.w * vb.w;
                    }
                    const float* pgb = selg + brow * 4;
                    float g0 = ga0 - pgb[0];
                    float g1 = ga1 - pgb[1];
                    float g2 = ga2 - pgb[2];
                    float gd = g0 * g0 + g1 * g1 + g2 * g2;
                    float s = 10.0f * __expf(-cd - gd * (1.0f / 0.3f))
                            +  3.0f * __expf(-10.0f * cd);
                    res[j] = -dot * s;
                }
            }
            *(f32x4*)(out + arow * NS + b4) = res;
        }
    }
}

extern "C" void kernel_launch(void* const* d_in, const int* in_sizes, int n_in,
                              void* d_out, int out_size, void* d_ws, size_t ws_size,
                              hipStream_t stream) {
    const float* guidance = (const float*)d_in[0];
    const float* clusters = (const float*)d_in[1];
    const int*   coords   = (const int*)d_in[2];
    float* out = (float*)d_out;
    float* ws  = (float*)d_ws;

    {
        int total = NB * NS * 32;
        int blocks = (total + 255) / 256;
        crf_gather<<<blocks, 256, 0, stream>>>(guidance, clusters, coords, ws);
    }
    {
        int blocks = NB * NCHUNK;   // 3200
        crf_main<<<blocks, 256, 0, stream>>>(ws, out);
    }
}